// Round 5
// baseline (39.384 us; speedup 1.0000x reference)
//
#include <hip/hip_runtime.h>

#define HW_ 25600            // 160*160
#define CHW_ (32 * 25600)    // C*H*W
#define NPIX 819200          // 32*160*160
#define ROWB 40              // ushorts per LDS stats row (80 B -> spreads banks)

typedef short bf16x8 __attribute__((ext_vector_type(8)));
typedef float f32x4 __attribute__((ext_vector_type(4)));

__device__ __forceinline__ unsigned short f2bf(float f) {
    unsigned int u = __float_as_uint(f);               // RNE round to bf16
    return (unsigned short)((u + 0x7FFFu + ((u >> 16) & 1u)) >> 16);
}

// B fragments for mfma_f32_16x16x32_bf16 (+ bias trick):
// w1f[(nt*64 + lane)*8 + i] = B[k=(lane>>4)*8+i][col=nt*16+(lane&15)]
//   k<16 : w1e[col][k] = w1[col*20+g*5+idx] + 0.25*w1[col*20+g*5+4]  (mean folded)
//   k==16: b1[col]   (A supplies 1.0 at k=16)
//   else : 0
__global__ void dgqp_prep(const float* __restrict__ w1,
                          const float* __restrict__ b1,
                          unsigned short* __restrict__ w1f) {
    int t = threadIdx.x;                 // 0..255
    int lane = t & 63;
    int col = ((t >> 6) << 4) | (lane & 15);
    int kg = lane >> 4;
    unsigned int pk[4];
    #pragma unroll
    for (int pr = 0; pr < 4; ++pr) {
        unsigned short hh[2];
        #pragma unroll
        for (int e = 0; e < 2; ++e) {
            int k = kg * 8 + pr * 2 + e;
            float v = 0.f;
            if (k < 16) {
                int g = k >> 2, idx = k & 3;
                v = w1[col * 20 + g * 5 + idx] + 0.25f * w1[col * 20 + g * 5 + 4];
            } else if (k == 16) {
                v = b1[col];
            }
            hh[e] = f2bf(v);
        }
        pk[pr] = (unsigned int)hh[0] | ((unsigned int)hh[1] << 16);
    }
    *reinterpret_cast<uint4*>(w1f + t * 8) = make_uint4(pk[0], pk[1], pk[2], pk[3]);
}

// 1 px/thread softmax+top4 -> bf16 stats in LDS -> 16x MFMA (64px x 64out, K=32)
// -> relu*w2 partials -> 16-lane shfl reduce -> sigmoid -> store.
// __launch_bounds__(256,4): 4 waves/SIMD min -> 128-VGPR budget. Without the
// hint the compiler capped at 48 VGPRs and spilled v[32] (round-4 counters:
// WRITE_SIZE 54.4MB vs 3.2MB output = ~51MB scratch writes).
__global__ __launch_bounds__(256, 4) void dgqp_main(
    const float* __restrict__ x,
    const unsigned short* __restrict__ w1f,   // [4][64][8] bf16 fragments
    const float* __restrict__ w2,             // [64]
    const float* __restrict__ b2,             // [1]
    float* __restrict__ out)                  // [819200]
{
    __shared__ unsigned short lds[256 * ROWB];   // 20 KB

    const int tid  = threadIdx.x;
    const int lane = tid & 63;
    const int wb   = tid & 192;                  // wave base pixel (wv*64)
    const int q    = lane & 15;
    const int kg   = lane >> 4;
    const int px   = blockIdx.x * 256 + tid;
    const unsigned int n = (unsigned int)px / HW_;
    const unsigned int off = (unsigned int)px + n * (unsigned int)(CHW_ - HW_);

    // all 32 channel loads up front (coalesced 4B/lane)
    float v[32];
    #pragma unroll
    for (int c = 0; c < 32; ++c) v[c] = x[(size_t)off + (size_t)c * HW_];

    // softmax + sorted top-4 per group (no max-subtract: x~N(0,1), fp32-safe;
    // top-4 of exp == top-4 of x). Results as packed bf16.
    unsigned int hp[8];
    #pragma unroll
    for (int g = 0; g < 4; ++g) {
        float sum = 0.f, t0 = 0.f, t1 = 0.f, t2 = 0.f, t3 = 0.f;
        #pragma unroll
        for (int b = 0; b < 8; ++b) {
            float e = __expf(v[g * 8 + b]);
            sum += e;
            float u0 = fminf(t0, e);  t0 = fmaxf(t0, e);
            float u1 = fminf(t1, u0); t1 = fmaxf(t1, u0);
            float u2 = fminf(t2, u1); t2 = fmaxf(t2, u1);
            t3 = fmaxf(t3, u2);
        }
        float inv = __builtin_amdgcn_rcpf(sum);
        hp[g * 2]     = (unsigned int)f2bf(t0 * inv) | ((unsigned int)f2bf(t1 * inv) << 16);
        hp[g * 2 + 1] = (unsigned int)f2bf(t2 * inv) | ((unsigned int)f2bf(t3 * inv) << 16);
    }

    // stats row: k0-15 = stats, k16 = 1.0 (bias slot), k17-31 = 0
    unsigned short* row = lds + tid * ROWB;
    *reinterpret_cast<uint4*>(row)      = make_uint4(hp[0], hp[1], hp[2], hp[3]);
    *reinterpret_cast<uint4*>(row + 8)  = make_uint4(hp[4], hp[5], hp[6], hp[7]);
    *reinterpret_cast<uint4*>(row + 16) = make_uint4(0x3F80u, 0u, 0u, 0u);  // bf16 1.0
    *reinterpret_cast<uint4*>(row + 24) = make_uint4(0u, 0u, 0u, 0u);
    __syncthreads();

    // A fragments: row = wave-local pixel (l&15 within 16-px mtile), k=(l>>4)*8+i
    bf16x8 afrag[4];
    #pragma unroll
    for (int m = 0; m < 4; ++m)
        afrag[m] = *reinterpret_cast<const bf16x8*>(lds + (wb + m * 16 + q) * ROWB + kg * 8);

    // B fragments (prebuilt, coalesced 16B/lane, L2-hot)
    bf16x8 bfrag[4];
    #pragma unroll
    for (int nt = 0; nt < 4; ++nt)
        bfrag[nt] = *reinterpret_cast<const bf16x8*>(w1f + (nt * 64 + lane) * 8);

    float w2l[4];
    #pragma unroll
    for (int nt = 0; nt < 4; ++nt) w2l[nt] = w2[nt * 16 + q];

    const f32x4 zero4 = {0.f, 0.f, 0.f, 0.f};
    float p[4][4];
    #pragma unroll
    for (int m = 0; m < 4; ++m)
        #pragma unroll
        for (int j = 0; j < 4; ++j) p[m][j] = 0.f;

    // D[px, out] tiles; epilogue folds layer 2: p += w2[ch]*relu(d)
    #pragma unroll
    for (int nt = 0; nt < 4; ++nt) {
        f32x4 d[4];
        #pragma unroll
        for (int m = 0; m < 4; ++m)
            d[m] = __builtin_amdgcn_mfma_f32_16x16x32_bf16(afrag[m], bfrag[nt], zero4, 0, 0, 0);
        #pragma unroll
        for (int m = 0; m < 4; ++m)
            #pragma unroll
            for (int j = 0; j < 4; ++j)
                p[m][j] = fmaf(w2l[nt], fmaxf(d[m][j], 0.f), p[m][j]);
    }

    // sum the 64 channels: reduce across the 16 lanes of each row-group
    #pragma unroll
    for (int m = 0; m < 4; ++m)
        #pragma unroll
        for (int j = 0; j < 4; ++j) {
            float r = p[m][j];
            r += __shfl_xor(r, 1);
            r += __shfl_xor(r, 2);
            r += __shfl_xor(r, 4);
            r += __shfl_xor(r, 8);
            p[m][j] = r;
        }

    // lane g*16+q (q<4) owns pixel wb + m*16 + g*4 + q  (C/D: row=(l>>4)*4+j)
    const float bb2 = b2[0];
    if (q < 4) {
        #pragma unroll
        for (int m = 0; m < 4; ++m) {
            float r = p[m][0];
            if (q == 1) r = p[m][1];
            if (q == 2) r = p[m][2];
            if (q == 3) r = p[m][3];
            float y = __builtin_amdgcn_rcpf(1.f + __expf(-(r + bb2)));
            out[blockIdx.x * 256 + wb + m * 16 + kg * 4 + q] = y;
        }
    }
}

extern "C" void kernel_launch(void* const* d_in, const int* in_sizes, int n_in,
                              void* d_out, int out_size, void* d_ws, size_t ws_size,
                              hipStream_t stream) {
    const float* x  = (const float*)d_in[0];
    const float* w1 = (const float*)d_in[1];
    const float* b1 = (const float*)d_in[2];
    const float* w2 = (const float*)d_in[3];
    const float* b2 = (const float*)d_in[4];
    float* out = (float*)d_out;
    unsigned short* w1f = (unsigned short*)d_ws;   // 2048 bf16 = 4 KB scratch

    dgqp_prep<<<1, 256, 0, stream>>>(w1, b1, w1f);
    dgqp_main<<<NPIX / 256, 256, 0, stream>>>(x, w1f, w2, b2, out);
}

// Round 6
// 32.066 us; speedup vs baseline: 1.2282x; 1.2282x over previous
//
#include <hip/hip_runtime.h>

#define HW_ 25600            // 160*160
#define CHW_ (32 * 25600)    // C*H*W
#define NPIX 819200          // 32*160*160
#define ROWB 40              // ushorts per LDS stats row (80 B -> spreads banks)

typedef short bf16x8 __attribute__((ext_vector_type(8)));
typedef float f32x4 __attribute__((ext_vector_type(4)));

__device__ __forceinline__ unsigned short f2bf(float f) {
    unsigned int u = __float_as_uint(f);               // RNE round to bf16
    return (unsigned short)((u + 0x7FFFu + ((u >> 16) & 1u)) >> 16);
}

// B fragments for mfma_f32_16x16x32_bf16 (+ bias trick):
// w1f[(nt*64 + lane)*8 + i] = B[k=(lane>>4)*8+i][col=nt*16+(lane&15)]
//   k<16 : w1e[col][k] = w1[col*20+g*5+idx] + 0.25*w1[col*20+g*5+4]  (mean folded)
//   k==16: b1[col]   (A supplies 1.0 at k=16)
//   else : 0
__global__ void dgqp_prep(const float* __restrict__ w1,
                          const float* __restrict__ b1,
                          unsigned short* __restrict__ w1f) {
    int t = threadIdx.x;                 // 0..255
    int lane = t & 63;
    int col = ((t >> 6) << 4) | (lane & 15);
    int kg = lane >> 4;
    unsigned int pk[4];
    #pragma unroll
    for (int pr = 0; pr < 4; ++pr) {
        unsigned short hh[2];
        #pragma unroll
        for (int e = 0; e < 2; ++e) {
            int k = kg * 8 + pr * 2 + e;
            float v = 0.f;
            if (k < 16) {
                int g = k >> 2, idx = k & 3;
                v = w1[col * 20 + g * 5 + idx] + 0.25f * w1[col * 20 + g * 5 + 4];
            } else if (k == 16) {
                v = b1[col];
            }
            hh[e] = f2bf(v);
        }
        pk[pr] = (unsigned int)hh[0] | ((unsigned int)hh[1] << 16);
    }
    *reinterpret_cast<uint4*>(w1f + t * 8) = make_uint4(pk[0], pk[1], pk[2], pk[3]);
}

// softmax+top4 (2-deep pipelined group loop) -> bf16 stats in LDS ->
// m-outer MFMA with immediate per-m reduce+store. All phases stay < ~44
// live VGPRs so even a 48-reg allocation has zero scratch spill (round-4/5
// counters showed ~51 MB of spill stores from the fat-epilogue version).
__global__ __launch_bounds__(256) void dgqp_main(
    const float* __restrict__ x,
    const unsigned short* __restrict__ w1f,   // [4][64][8] bf16 fragments
    const float* __restrict__ w2,             // [64]
    const float* __restrict__ b2,             // [1]
    float* __restrict__ out)                  // [819200]
{
    __shared__ unsigned short lds[256 * ROWB];   // 20 KB

    const int tid  = threadIdx.x;
    const int lane = tid & 63;
    const int wb   = tid & 192;                  // wave base pixel (wv*64)
    const int q    = lane & 15;
    const int kg   = lane >> 4;
    const int px   = blockIdx.x * 256 + tid;
    const unsigned int n = (unsigned int)px / HW_;
    const unsigned int off = (unsigned int)px + n * (unsigned int)(CHW_ - HW_);
    const float* xp = x + off;

    // ---- softmax + sorted top-4, 2-deep pipelined over the 4 groups ----
    // (no max-subtract: x~N(0,1), fp32-safe; top-4 of exp == top-4 of x)
    unsigned int hp[8];

#define PROC(g, buf) do {                                                   \
        float sum = 0.f, t0 = 0.f, t1 = 0.f, t2 = 0.f, t3 = 0.f;            \
        _Pragma("unroll")                                                   \
        for (int b = 0; b < 8; ++b) {                                       \
            float e = __expf(buf[b]);                                       \
            sum += e;                                                       \
            float u0 = fminf(t0, e);  t0 = fmaxf(t0, e);                    \
            float u1 = fminf(t1, u0); t1 = fmaxf(t1, u0);                   \
            float u2 = fminf(t2, u1); t2 = fmaxf(t2, u1);                   \
            t3 = fmaxf(t3, u2);                                             \
        }                                                                   \
        float inv = __builtin_amdgcn_rcpf(sum);                             \
        hp[(g)*2]   = (unsigned)f2bf(t0*inv) | ((unsigned)f2bf(t1*inv)<<16);\
        hp[(g)*2+1] = (unsigned)f2bf(t2*inv) | ((unsigned)f2bf(t3*inv)<<16);\
    } while (0)

    float va[8], vb[8];
    #pragma unroll
    for (int b = 0; b < 8; ++b) va[b] = xp[(size_t)b * HW_];
    #pragma unroll
    for (int b = 0; b < 8; ++b) vb[b] = xp[(size_t)(8 + b) * HW_];
    __builtin_amdgcn_sched_barrier(0);
    PROC(0, va);
    #pragma unroll
    for (int b = 0; b < 8; ++b) va[b] = xp[(size_t)(16 + b) * HW_];
    __builtin_amdgcn_sched_barrier(0);
    PROC(1, vb);
    #pragma unroll
    for (int b = 0; b < 8; ++b) vb[b] = xp[(size_t)(24 + b) * HW_];
    __builtin_amdgcn_sched_barrier(0);
    PROC(2, va);
    __builtin_amdgcn_sched_barrier(0);
    PROC(3, vb);
#undef PROC

    // stats row: k0-15 = stats, k16 = 1.0 (bias slot), k17-31 = 0
    unsigned short* row = lds + tid * ROWB;
    *reinterpret_cast<uint4*>(row)      = make_uint4(hp[0], hp[1], hp[2], hp[3]);
    *reinterpret_cast<uint4*>(row + 8)  = make_uint4(hp[4], hp[5], hp[6], hp[7]);
    *reinterpret_cast<uint4*>(row + 16) = make_uint4(0x3F80u, 0u, 0u, 0u);  // bf16 1.0
    *reinterpret_cast<uint4*>(row + 24) = make_uint4(0u, 0u, 0u, 0u);
    __syncthreads();

    // ---- MFMA phase, m-outer so only one afrag / pm / d live at a time ----
    // B fragments (prebuilt, coalesced 16B/lane, L2-hot): 16 regs resident
    bf16x8 bfrag[4];
    #pragma unroll
    for (int nt = 0; nt < 4; ++nt)
        bfrag[nt] = *reinterpret_cast<const bf16x8*>(w1f + (nt * 64 + lane) * 8);

    float w2l[4];
    #pragma unroll
    for (int nt = 0; nt < 4; ++nt) w2l[nt] = w2[nt * 16 + q];

    const f32x4 zero4 = {0.f, 0.f, 0.f, 0.f};
    const float bb2 = b2[0];
    const int outbase = blockIdx.x * 256 + wb;

    #pragma unroll
    for (int m = 0; m < 4; ++m) {
        // A fragment: row = wave-local pixel (q within 16-px mtile), k=(kg)*8+i
        bf16x8 afrag = *reinterpret_cast<const bf16x8*>(
            lds + (wb + m * 16 + q) * ROWB + kg * 8);

        float pm0 = 0.f, pm1 = 0.f, pm2 = 0.f, pm3 = 0.f;
        #pragma unroll
        for (int nt = 0; nt < 4; ++nt) {
            f32x4 d = __builtin_amdgcn_mfma_f32_16x16x32_bf16(afrag, bfrag[nt], zero4, 0, 0, 0);
            pm0 = fmaf(w2l[nt], fmaxf(d[0], 0.f), pm0);
            pm1 = fmaf(w2l[nt], fmaxf(d[1], 0.f), pm1);
            pm2 = fmaf(w2l[nt], fmaxf(d[2], 0.f), pm2);
            pm3 = fmaf(w2l[nt], fmaxf(d[3], 0.f), pm3);
        }
        // sum the 64 channels: reduce across the 16 lanes of each row-group
        #pragma unroll
        for (int sh = 1; sh < 16; sh <<= 1) {
            pm0 += __shfl_xor(pm0, sh);
            pm1 += __shfl_xor(pm1, sh);
            pm2 += __shfl_xor(pm2, sh);
            pm3 += __shfl_xor(pm3, sh);
        }
        // lane kg*16+q (q<4) owns pixel wb + m*16 + kg*4 + q (C/D row=(l>>4)*4+j)
        if (q < 4) {
            float r = pm0;
            if (q == 1) r = pm1;
            if (q == 2) r = pm2;
            if (q == 3) r = pm3;
            float y = __builtin_amdgcn_rcpf(1.f + __expf(-(r + bb2)));
            out[outbase + m * 16 + kg * 4 + q] = y;
        }
    }
}

extern "C" void kernel_launch(void* const* d_in, const int* in_sizes, int n_in,
                              void* d_out, int out_size, void* d_ws, size_t ws_size,
                              hipStream_t stream) {
    const float* x  = (const float*)d_in[0];
    const float* w1 = (const float*)d_in[1];
    const float* b1 = (const float*)d_in[2];
    const float* w2 = (const float*)d_in[3];
    const float* b2 = (const float*)d_in[4];
    float* out = (float*)d_out;
    unsigned short* w1f = (unsigned short*)d_ws;   // 2048 bf16 = 4 KB scratch

    dgqp_prep<<<1, 256, 0, stream>>>(w1, b1, w1f);
    dgqp_main<<<NPIX / 256, 256, 0, stream>>>(x, w1f, w2, b2, out);
}